// Round 11
// baseline (69.376 us; speedup 1.0000x reference)
//
#include <hip/hip_runtime.h>
#include <hip/hip_bf16.h>
#include <math.h>

#define NROWS 131072
#define NCODE 512
#define DIM 128
#define ESCALE 256.0f       // emb * 2^8 into fp8 (raw |e|~0.001 underflows e4m3)
#define DESCALE 0.0078125f  // 2/256: sv = e2 - 2*dot = e2 - DESCALE*acc

typedef long long llong;
typedef __attribute__((ext_vector_type(16))) float f32x16;

// ||e||^2 per code (fp32 exact), written in D-fragment order:
//   e2p[mt*32 + g*16 + r] = e2[mt*32 + (r&3) + 8*(r>>2) + 4*g]
__global__ void e2p_kernel(const float* __restrict__ emb, float* __restrict__ e2p) {
    int code = blockIdx.x * blockDim.x + threadIdx.x;
    if (code < NCODE) {
        const float4* e = reinterpret_cast<const float4*>(emb + (size_t)code * DIM);
        float s = 0.f;
        #pragma unroll
        for (int j = 0; j < 32; ++j) {
            float4 v = e[j];
            s = fmaf(v.x, v.x, s); s = fmaf(v.y, v.y, s);
            s = fmaf(v.z, v.z, s); s = fmaf(v.w, v.w, s);
        }
        int mt = code >> 5, c5 = code & 31;
        int g = (c5 >> 2) & 1;
        int r = (c5 & 3) | ((c5 >> 3) << 2);
        e2p[mt * 32 + g * 16 + r] = s;
    }
}

// Pack emb*256 into fp8 A-fragment lane order:
//   afp[(mt*4+q)*64 + lane] = 16B: bytes[h*8+j] = fp8(emb[mt*32+(lane&31)][(2q+h)*16+(lane>>5)*8+j]*256)
__global__ __launch_bounds__(256) void prep_pack8(const float* __restrict__ emb,
        int4* __restrict__ afp) {
    int gid = blockIdx.x * 256 + threadIdx.x;      // 16 blocks x 256 = 4096
    int lane = gid & 63, q = (gid >> 6) & 3, mt = gid >> 8;
    int code = mt * 32 + (lane & 31);
    int g = lane >> 5;
    const float* src = emb + (size_t)code * DIM;
    int w[4];
    #pragma unroll
    for (int h = 0; h < 2; ++h) {
        int d0 = (2 * q + h) * 16 + g * 8;
        float4 v0 = *reinterpret_cast<const float4*>(src + d0);
        float4 v1 = *reinterpret_cast<const float4*>(src + d0 + 4);
        int lo = __builtin_amdgcn_cvt_pk_fp8_f32(v0.x * ESCALE, v0.y * ESCALE, 0, false);
        lo = __builtin_amdgcn_cvt_pk_fp8_f32(v0.z * ESCALE, v0.w * ESCALE, lo, true);
        int hi = __builtin_amdgcn_cvt_pk_fp8_f32(v1.x * ESCALE, v1.y * ESCALE, 0, false);
        hi = __builtin_amdgcn_cvt_pk_fp8_f32(v1.z * ESCALE, v1.w * ESCALE, hi, true);
        w[2 * h] = lo; w[2 * h + 1] = hi;
    }
    afp[gid] = make_int4(w[0], w[1], w[2], w[3]);
}

__device__ inline llong mk_ll(int lo, int hi) {
    return ((llong)(unsigned long long)(unsigned)hi << 32) | (unsigned)lo;
}

// TLP design: block = 4 waves = 2 row-groups (rg) x 2 code-halves (ch).
// Wave: 32 rows x 256 codes (8 M-tiles), fp8 MFMA, regs <= 64 -> 8 waves/SIMD.
// 8192 waves total. Merge code-halves via LDS; fused gather.
__global__ __launch_bounds__(256, 8) void vq_argmin(
        const float* __restrict__ x, const float* __restrict__ emb,
        const int4* __restrict__ afp, const float* __restrict__ e2p,
        int* __restrict__ idxg,
        float* __restrict__ out0, float* __restrict__ out1, float* __restrict__ out2) {
    __shared__ float s_m[2][2][32];
    __shared__ int   s_i[2][2][32];
    __shared__ int   s_fidx[2][32];

    const int tid = threadIdx.x;
    const int lane = tid & 63, l31 = lane & 31, g = lane >> 5;
    const int w = tid >> 6, rg = w >> 1, ch = w & 1;
    const long row0 = (long)blockIdx.x * 64;
    const long rowbase = row0 + rg * 32;

    // ---- load rows -> fp8 B-fragments (8 x llong = 16 VGPR), fuse x2 ----
    llong b0, b1, b2, b3, b4, b5, b6, b7;
    float xsq = 0.f;
    {
        const float* xrow = x + (rowbase + l31) * DIM + g * 8;
        #define LOADB(KK, B) {                                             \
            float4 v0 = *reinterpret_cast<const float4*>(xrow + KK * 16);  \
            float4 v1 = *reinterpret_cast<const float4*>(xrow + KK * 16 + 4); \
            xsq = fmaf(v0.x, v0.x, xsq); xsq = fmaf(v0.y, v0.y, xsq);      \
            xsq = fmaf(v0.z, v0.z, xsq); xsq = fmaf(v0.w, v0.w, xsq);      \
            xsq = fmaf(v1.x, v1.x, xsq); xsq = fmaf(v1.y, v1.y, xsq);      \
            xsq = fmaf(v1.z, v1.z, xsq); xsq = fmaf(v1.w, v1.w, xsq);      \
            int lo = __builtin_amdgcn_cvt_pk_fp8_f32(v0.x, v0.y, 0, false); \
            lo = __builtin_amdgcn_cvt_pk_fp8_f32(v0.z, v0.w, lo, true);    \
            int hi = __builtin_amdgcn_cvt_pk_fp8_f32(v1.x, v1.y, 0, false); \
            hi = __builtin_amdgcn_cvt_pk_fp8_f32(v1.z, v1.w, hi, true);    \
            B = mk_ll(lo, hi); }
        LOADB(0, b0) LOADB(1, b1) LOADB(2, b2) LOADB(3, b3)
        LOADB(4, b4) LOADB(5, b5) LOADB(6, b6) LOADB(7, b7)
        #undef LOADB
        xsq += __shfl_xor(xsq, 32);   // complementary k-chunks -> full ||x_row||^2
    }

    float m1 = 1e30f;
    int i1 = 0;

    // ---- 8 M-tiles (codes ch*256 .. +256); 4 A-loads + 8 MFMA per tile ----
    #pragma unroll 1
    for (int t = 0; t < 8; ++t) {
        const int mt = ch * 8 + t;
        const int4* ap = afp + mt * 256 + lane;
        int4 A0 = ap[0];
        int4 A1 = ap[64];
        int4 A2 = ap[128];
        int4 A3 = ap[192];
        f32x16 acc = {};
        acc = __builtin_amdgcn_mfma_f32_32x32x16_fp8_fp8(mk_ll(A0.x, A0.y), b0, acc, 0, 0, 0);
        acc = __builtin_amdgcn_mfma_f32_32x32x16_fp8_fp8(mk_ll(A0.z, A0.w), b1, acc, 0, 0, 0);
        acc = __builtin_amdgcn_mfma_f32_32x32x16_fp8_fp8(mk_ll(A1.x, A1.y), b2, acc, 0, 0, 0);
        acc = __builtin_amdgcn_mfma_f32_32x32x16_fp8_fp8(mk_ll(A1.z, A1.w), b3, acc, 0, 0, 0);
        acc = __builtin_amdgcn_mfma_f32_32x32x16_fp8_fp8(mk_ll(A2.x, A2.y), b4, acc, 0, 0, 0);
        acc = __builtin_amdgcn_mfma_f32_32x32x16_fp8_fp8(mk_ll(A2.z, A2.w), b5, acc, 0, 0, 0);
        acc = __builtin_amdgcn_mfma_f32_32x32x16_fp8_fp8(mk_ll(A3.x, A3.y), b6, acc, 0, 0, 0);
        acc = __builtin_amdgcn_mfma_f32_32x32x16_fp8_fp8(mk_ll(A3.z, A3.w), b7, acc, 0, 0, 0);

        const float4* ev = reinterpret_cast<const float4*>(e2p + mt * 32 + g * 16);
        const int base = mt * 32 + 4 * g;
        float4 ea = ev[0], eb = ev[1];
        float e8a[8] = {ea.x, ea.y, ea.z, ea.w, eb.x, eb.y, eb.z, eb.w};
        #pragma unroll
        for (int r = 0; r < 8; ++r) {
            float sv = e8a[r] - DESCALE * acc[r];
            int code = base + (r & 3) + 8 * (r >> 2);
            if (sv < m1) { m1 = sv; i1 = code; }
        }
        float4 ec = ev[2], ed = ev[3];
        float e8b[8] = {ec.x, ec.y, ec.z, ec.w, ed.x, ed.y, ed.z, ed.w};
        #pragma unroll
        for (int r = 0; r < 8; ++r) {
            float sv = e8b[r] - DESCALE * acc[8 + r];
            int code = base + 16 + (r & 3) + 8 * (r >> 2);
            if (sv < m1) { m1 = sv; i1 = code; }
        }
    }

    // merge the two g-halves (same row on lane and lane^32)
    {
        float pm = __shfl_xor(m1, 32);
        int   pi = __shfl_xor(i1, 32);
        if (pm < m1 || (pm == m1 && pi < i1)) { m1 = pm; i1 = pi; }
    }
    if (lane < 32) { s_m[rg][ch][l31] = m1; s_i[rg][ch][l31] = i1; }
    __syncthreads();

    // ---- merge code-halves; write idx/out1/out2 (ch0 wave) ----
    if (ch == 0 && lane < 32) {
        float m1f = s_m[rg][0][l31]; int i1f = s_i[rg][0][l31];
        float pm = s_m[rg][1][l31]; int pi = s_i[rg][1][l31];
        if (pm < m1f || (pm == m1f && pi < i1f)) { m1f = pm; i1f = pi; }
        long row = rowbase + l31;
        idxg[row] = i1f;
        s_fidx[rg][l31] = i1f;
        float o = xsq + m1f;   // ||x||^2 + (||e||^2 - 2 x.e); err ~1e-3 << 4.24
        out1[row] = o;
        out2[row] = o;
    }
    __syncthreads();

    // ---- fused gather: each wave writes 16 rows (2 rows/iter, half-wave each) ----
    {
        const float4* e4 = reinterpret_cast<const float4*>(emb);
        float4* o4 = reinterpret_cast<float4*>(out0);
        const int rb = rg * 32 + ch * 16;
        #pragma unroll 4
        for (int rr = 0; rr < 16; rr += 2) {
            int lr = rb + rr + g;                 // local row in [0,64)
            int c = s_fidx[rg][ch * 16 + rr + g];
            o4[(row0 + lr) * 32 + l31] = e4[c * 32 + l31];
        }
    }
}

// Histogram (LDS) + entropy in one block.
__global__ __launch_bounds__(1024) void hist_entropy(const int* __restrict__ idxg,
        float* __restrict__ oent) {
    __shared__ int h[NCODE];
    __shared__ float red[16];
    int tid = threadIdx.x;
    if (tid < NCODE) h[tid] = 0;
    __syncthreads();
    const int4* i4 = reinterpret_cast<const int4*>(idxg);
    #pragma unroll
    for (int k = 0; k < 32; ++k) {
        int4 v = i4[tid + k * 1024];
        atomicAdd(&h[v.x], 1); atomicAdd(&h[v.y], 1);
        atomicAdd(&h[v.z], 1); atomicAdd(&h[v.w], 1);
    }
    __syncthreads();
    float t = 0.f;
    if (tid < NCODE) {
        float p = (float)h[tid] * (1.0f / 131072.0f);
        t = (p > 0.f) ? (-p * logf(p)) : 0.f;
    }
    #pragma unroll
    for (int off = 32; off > 0; off >>= 1) t += __shfl_down(t, off);
    if ((tid & 63) == 0) red[tid >> 6] = t;
    __syncthreads();
    if (tid == 0) {
        float s = 0.f;
        #pragma unroll
        for (int i = 0; i < 16; ++i) s += red[i];
        *oent = s;
    }
}

extern "C" void kernel_launch(void* const* d_in, const int* in_sizes, int n_in,
                              void* d_out, int out_size, void* d_ws, size_t ws_size,
                              hipStream_t stream) {
    const float* x   = (const float*)d_in[0];
    const float* emb = (const float*)d_in[1];
    float* out  = (float*)d_out;
    float* out0 = out;
    float* out1 = out0 + (size_t)NROWS * DIM;
    float* out2 = out1 + NROWS;
    float* oent = out2 + NROWS;

    float* e2p = (float*)d_ws;                                  // 2 KB
    int4*  afp = (int4*)((char*)d_ws + 4096);                   // 64 KB
    int*   idxg = (int*)((char*)d_ws + 4096 + 65536);           // 512 KB

    e2p_kernel<<<2, 256, 0, stream>>>(emb, e2p);
    prep_pack8<<<16, 256, 0, stream>>>(emb, afp);
    vq_argmin<<<NROWS / 64, 256, 0, stream>>>(x, emb, afp, e2p, idxg, out0, out1, out2);
    hist_entropy<<<1, 1024, 0, stream>>>(idxg, oent);
}

// Round 12
// 62.816 us; speedup vs baseline: 1.1044x; 1.1044x over previous
//
#include <hip/hip_runtime.h>
#include <hip/hip_bf16.h>
#include <math.h>

#define NROWS 131072
#define NCODE 512
#define DIM 128
#define ESCALE 256.0f       // emb * 2^8 into fp8 (raw |e|~0.001 underflows e4m3)
#define DESCALE 0.0078125f  // 2/256: sv = e2 - 2*dot = e2 - DESCALE*acc

typedef long long llong;
typedef __attribute__((ext_vector_type(16))) float f32x16;

// ||e||^2 per code (fp32 exact), written in D-fragment order:
//   e2p[mt*32 + g*16 + r] = e2[mt*32 + (r&3) + 8*(r>>2) + 4*g]
__global__ void e2p_kernel(const float* __restrict__ emb, float* __restrict__ e2p) {
    int code = blockIdx.x * blockDim.x + threadIdx.x;
    if (code < NCODE) {
        const float4* e = reinterpret_cast<const float4*>(emb + (size_t)code * DIM);
        float s = 0.f;
        #pragma unroll
        for (int j = 0; j < 32; ++j) {
            float4 v = e[j];
            s = fmaf(v.x, v.x, s); s = fmaf(v.y, v.y, s);
            s = fmaf(v.z, v.z, s); s = fmaf(v.w, v.w, s);
        }
        int mt = code >> 5, c5 = code & 31;
        int g = (c5 >> 2) & 1;
        int r = (c5 & 3) | ((c5 >> 3) << 2);
        e2p[mt * 32 + g * 16 + r] = s;
    }
}

// Pack emb*256 into fp8 A-fragment lane order:
//   afp[(mt*4+q)*64 + lane] = 16B: bytes[h*8+j] = fp8(emb[mt*32+(lane&31)][(2q+h)*16+(lane>>5)*8+j]*256)
__global__ __launch_bounds__(256) void prep_pack8(const float* __restrict__ emb,
        int4* __restrict__ afp) {
    int gid = blockIdx.x * 256 + threadIdx.x;      // 16 blocks x 256 = 4096
    int lane = gid & 63, q = (gid >> 6) & 3, mt = gid >> 8;
    int code = mt * 32 + (lane & 31);
    int g = lane >> 5;
    const float* src = emb + (size_t)code * DIM;
    int w[4];
    #pragma unroll
    for (int h = 0; h < 2; ++h) {
        int d0 = (2 * q + h) * 16 + g * 8;
        float4 v0 = *reinterpret_cast<const float4*>(src + d0);
        float4 v1 = *reinterpret_cast<const float4*>(src + d0 + 4);
        int lo = __builtin_amdgcn_cvt_pk_fp8_f32(v0.x * ESCALE, v0.y * ESCALE, 0, false);
        lo = __builtin_amdgcn_cvt_pk_fp8_f32(v0.z * ESCALE, v0.w * ESCALE, lo, true);
        int hi = __builtin_amdgcn_cvt_pk_fp8_f32(v1.x * ESCALE, v1.y * ESCALE, 0, false);
        hi = __builtin_amdgcn_cvt_pk_fp8_f32(v1.z * ESCALE, v1.w * ESCALE, hi, true);
        w[2 * h] = lo; w[2 * h + 1] = hi;
    }
    afp[gid] = make_int4(w[0], w[1], w[2], w[3]);
}

__device__ inline llong mk_ll(int lo, int hi) {
    return ((llong)(unsigned long long)(unsigned)hi << 32) | (unsigned)lo;
}

// Block = 4 waves = 2 row-groups x 2 code-halves; 64 rows x 512 codes.
// x ingested ONCE per block, fully coalesced, fp8-packed into swizzled LDS;
// x2 computed in the same pass via 32-lane shuffle reduce (exact fp32).
// Each wave: 32 rows x 256 codes (8 M-tiles), A streamed from L2-hot afp.
__global__ __launch_bounds__(256, 8) void vq_argmin(
        const float* __restrict__ x, const float* __restrict__ emb,
        const int4* __restrict__ afp, const float* __restrict__ e2p,
        int* __restrict__ idxg,
        float* __restrict__ out0, float* __restrict__ out1, float* __restrict__ out2) {
    __shared__ unsigned char xs8[64][DIM];   // fp8 rows, byte off ^= ((row&15)<<3)
    __shared__ float x2s[64];
    __shared__ float s_m[2][2][32];
    __shared__ int   s_i[2][2][32];
    __shared__ int   s_fidx[2][32];

    const int tid = threadIdx.x;
    const int lane = tid & 63, l31 = lane & 31, g = lane >> 5;
    const long row0 = (long)blockIdx.x * 64;

    // ---- coalesced ingest: per it, each 32-lane group covers one full row ----
    {
        const float4* xg = reinterpret_cast<const float4*>(x + row0 * DIM);
        #pragma unroll
        for (int it = 0; it < 8; ++it) {
            float4 v = xg[it * 256 + tid];
            int r = it * 8 + (tid >> 5), c = tid & 31;
            // row ||x||^2: reduce across the 32 lanes holding this row
            float s = v.x * v.x + v.y * v.y + v.z * v.z + v.w * v.w;
            s += __shfl_xor(s, 1);  s += __shfl_xor(s, 2);
            s += __shfl_xor(s, 4);  s += __shfl_xor(s, 8);
            s += __shfl_xor(s, 16);
            if ((tid & 31) == 0) x2s[r] = s;
            // fp8 pack 4 floats -> 4 bytes, swizzled store (conflict-free)
            int w = __builtin_amdgcn_cvt_pk_fp8_f32(v.x, v.y, 0, false);
            w = __builtin_amdgcn_cvt_pk_fp8_f32(v.z, v.w, w, true);
            int off = (c * 4) ^ ((r & 15) << 3);
            *reinterpret_cast<int*>(&xs8[r][off]) = w;
        }
    }
    __syncthreads();

    const int wv = tid >> 6, rg = wv >> 1, ch = wv & 1;
    const int rr = rg * 32 + l31;               // local row this lane owns

    // ---- B-fragments from LDS (8 x 8B ds_read, once per wave) ----
    #define RB(K) *reinterpret_cast<const llong*>(&xs8[rr][((K) * 16 + g * 8) ^ ((rr & 15) << 3)])
    const llong b0 = RB(0), b1 = RB(1), b2 = RB(2), b3 = RB(3);
    const llong b4 = RB(4), b5 = RB(5), b6 = RB(6), b7 = RB(7);
    #undef RB

    float m1 = 1e30f;
    int i1 = 0;

    // ---- 8 M-tiles (codes ch*256 .. +256); 4 A-loads + 8 MFMA per tile ----
    #pragma unroll 1
    for (int t = 0; t < 8; ++t) {
        const int mt = ch * 8 + t;
        const int4* ap = afp + mt * 256 + lane;
        int4 A0 = ap[0];
        int4 A1 = ap[64];
        int4 A2 = ap[128];
        int4 A3 = ap[192];
        f32x16 acc = {};
        acc = __builtin_amdgcn_mfma_f32_32x32x16_fp8_fp8(mk_ll(A0.x, A0.y), b0, acc, 0, 0, 0);
        acc = __builtin_amdgcn_mfma_f32_32x32x16_fp8_fp8(mk_ll(A0.z, A0.w), b1, acc, 0, 0, 0);
        acc = __builtin_amdgcn_mfma_f32_32x32x16_fp8_fp8(mk_ll(A1.x, A1.y), b2, acc, 0, 0, 0);
        acc = __builtin_amdgcn_mfma_f32_32x32x16_fp8_fp8(mk_ll(A1.z, A1.w), b3, acc, 0, 0, 0);
        acc = __builtin_amdgcn_mfma_f32_32x32x16_fp8_fp8(mk_ll(A2.x, A2.y), b4, acc, 0, 0, 0);
        acc = __builtin_amdgcn_mfma_f32_32x32x16_fp8_fp8(mk_ll(A2.z, A2.w), b5, acc, 0, 0, 0);
        acc = __builtin_amdgcn_mfma_f32_32x32x16_fp8_fp8(mk_ll(A3.x, A3.y), b6, acc, 0, 0, 0);
        acc = __builtin_amdgcn_mfma_f32_32x32x16_fp8_fp8(mk_ll(A3.z, A3.w), b7, acc, 0, 0, 0);

        const float4* ev = reinterpret_cast<const float4*>(e2p + mt * 32 + g * 16);
        const int base = mt * 32 + 4 * g;
        float4 ea = ev[0], eb = ev[1];
        float e8a[8] = {ea.x, ea.y, ea.z, ea.w, eb.x, eb.y, eb.z, eb.w};
        #pragma unroll
        for (int r = 0; r < 8; ++r) {
            float sv = e8a[r] - DESCALE * acc[r];
            int code = base + (r & 3) + 8 * (r >> 2);
            if (sv < m1) { m1 = sv; i1 = code; }
        }
        float4 ec = ev[2], ed = ev[3];
        float e8b[8] = {ec.x, ec.y, ec.z, ec.w, ed.x, ed.y, ed.z, ed.w};
        #pragma unroll
        for (int r = 0; r < 8; ++r) {
            float sv = e8b[r] - DESCALE * acc[8 + r];
            int code = base + 16 + (r & 3) + 8 * (r >> 2);
            if (sv < m1) { m1 = sv; i1 = code; }
        }
    }

    // merge the two g-halves (same row on lane and lane^32)
    {
        float pm = __shfl_xor(m1, 32);
        int   pi = __shfl_xor(i1, 32);
        if (pm < m1 || (pm == m1 && pi < i1)) { m1 = pm; i1 = pi; }
    }
    if (lane < 32) { s_m[rg][ch][l31] = m1; s_i[rg][ch][l31] = i1; }
    __syncthreads();

    // ---- merge code-halves; write idx/out1/out2 (ch0 wave) ----
    if (ch == 0 && lane < 32) {
        float m1f = s_m[rg][0][l31]; int i1f = s_i[rg][0][l31];
        float pm = s_m[rg][1][l31]; int pi = s_i[rg][1][l31];
        if (pm < m1f || (pm == m1f && pi < i1f)) { m1f = pm; i1f = pi; }
        long row = row0 + rr;
        idxg[row] = i1f;
        s_fidx[rg][l31] = i1f;
        float o = x2s[rr] + m1f;   // ||x||^2 + (||e||^2 - 2 x.e); err ~1e-3 << 4.24
        out1[row] = o;
        out2[row] = o;
    }
    __syncthreads();

    // ---- fused gather: each wave writes 16 rows (2 rows/iter, half-wave each) ----
    {
        const float4* e4 = reinterpret_cast<const float4*>(emb);
        float4* o4 = reinterpret_cast<float4*>(out0);
        const int rb = rg * 32 + ch * 16;
        #pragma unroll 4
        for (int rx = 0; rx < 16; rx += 2) {
            int lr = rb + rx + g;                 // local row in [0,64)
            int c = s_fidx[rg][ch * 16 + rx + g];
            o4[(row0 + lr) * 32 + l31] = e4[c * 32 + l31];
        }
    }
}

// Histogram (LDS) + entropy in one block.
__global__ __launch_bounds__(1024) void hist_entropy(const int* __restrict__ idxg,
        float* __restrict__ oent) {
    __shared__ int h[NCODE];
    __shared__ float red[16];
    int tid = threadIdx.x;
    if (tid < NCODE) h[tid] = 0;
    __syncthreads();
    const int4* i4 = reinterpret_cast<const int4*>(idxg);
    #pragma unroll
    for (int k = 0; k < 32; ++k) {
        int4 v = i4[tid + k * 1024];
        atomicAdd(&h[v.x], 1); atomicAdd(&h[v.y], 1);
        atomicAdd(&h[v.z], 1); atomicAdd(&h[v.w], 1);
    }
    __syncthreads();
    float t = 0.f;
    if (tid < NCODE) {
        float p = (float)h[tid] * (1.0f / 131072.0f);
        t = (p > 0.f) ? (-p * logf(p)) : 0.f;
    }
    #pragma unroll
    for (int off = 32; off > 0; off >>= 1) t += __shfl_down(t, off);
    if ((tid & 63) == 0) red[tid >> 6] = t;
    __syncthreads();
    if (tid == 0) {
        float s = 0.f;
        #pragma unroll
        for (int i = 0; i < 16; ++i) s += red[i];
        *oent = s;
    }
}

extern "C" void kernel_launch(void* const* d_in, const int* in_sizes, int n_in,
                              void* d_out, int out_size, void* d_ws, size_t ws_size,
                              hipStream_t stream) {
    const float* x   = (const float*)d_in[0];
    const float* emb = (const float*)d_in[1];
    float* out  = (float*)d_out;
    float* out0 = out;
    float* out1 = out0 + (size_t)NROWS * DIM;
    float* out2 = out1 + NROWS;
    float* oent = out2 + NROWS;

    float* e2p = (float*)d_ws;                                  // 2 KB
    int4*  afp = (int4*)((char*)d_ws + 4096);                   // 64 KB
    int*   idxg = (int*)((char*)d_ws + 4096 + 65536);           // 512 KB

    e2p_kernel<<<2, 256, 0, stream>>>(emb, e2p);
    prep_pack8<<<16, 256, 0, stream>>>(emb, afp);
    vq_argmin<<<NROWS / 64, 256, 0, stream>>>(x, emb, afp, e2p, idxg, out0, out1, out2);
    hist_entropy<<<1, 1024, 0, stream>>>(idxg, oent);
}